// Round 20
// baseline (101.249 us; speedup 1.0000x reference)
//
#include <hip/hip_runtime.h>
#include <cstddef>
#include <cstdint>

// ReBased linear attention, round 20.
// r19 post-mortem: proj_fused LDS-read-bound (1024 b128/block at ~15cyc incl
// 8-way conflict; ~27us/CU of LDS reads). Fix: XOR swizzle on GEMM tiles,
// both-sides (rule 21): linear LDS dest + inverse-permuted GLOBAL source +
// XOR on read idx ((lr&7)<<3). Applied to proj_fused (both branches) + o-GEMM.
// attn / mega_cast frozen (r15/r17 verified).

typedef __attribute__((ext_vector_type(8)))  __bf16 bf16x8;
typedef __attribute__((ext_vector_type(2)))  __bf16 bf16x2;
typedef __attribute__((ext_vector_type(4)))  float  f32x4;
typedef __attribute__((ext_vector_type(16))) float  f32x16;
typedef __attribute__((ext_vector_type(8)))  unsigned short ushort8;
typedef __attribute__((ext_vector_type(4)))  unsigned short ushort4v;
typedef __attribute__((ext_vector_type(4)))  unsigned int   uint4v;

__device__ __forceinline__ unsigned short f2b(float f) {
    union { float f; unsigned u; } v; v.f = f;
    unsigned r = v.u + 0x7FFFu + ((v.u >> 16) & 1u);   // RNE
    return (unsigned short)(r >> 16);
}
__device__ __forceinline__ float b2f(unsigned short b) {
    union { unsigned u; float f; } v; v.u = ((unsigned)b) << 16;
    return v.f;
}
__device__ __forceinline__ unsigned pk2(float a, float b) {
    bf16x2 p; p[0] = (__bf16)a; p[1] = (__bf16)b;
    return __builtin_bit_cast(unsigned, p);
}

typedef const __attribute__((address_space(1))) void* gas_ptr;
typedef __attribute__((address_space(3))) void* las_ptr;

__device__ __forceinline__ void gload_lds16(const unsigned short* g, unsigned short* l) {
    // 16B/lane; LDS dest = wave-uniform base + lane*16
    __builtin_amdgcn_global_load_lds((gas_ptr)g, (las_ptr)l, 16, 0, 0);
}

// Swizzle (ushort-index domain, BK=32 tiles, 64B rows):
//   read:  idx = (row*32 + col) ^ ((row&7)<<3)  [row&7 == lr&7 for frag reads]
//   stage: lane l writes phys idx rb*512 + l*8; the logical data there is
//          row = rb*16 + ((l2^l4)|(l3<<1)|(l4<<2)|(l5<<3)),
//          col = ((l0^l2^l4)<<3)|((l1^l3)<<4)      (derived inverse, bijective)

// ---------------- bf16 MFMA GEMM, BK=32, swizzled (o-projection) ----------------
template <int BM, int BN, int OUTMODE>
__global__ __launch_bounds__(256) void gemm_mfma(const unsigned short* __restrict__ A,
                                                 const unsigned short* __restrict__ W,
                                                 void* __restrict__ Cout,
                                                 int M, int N, int K) {
    constexpr int BK = 32;
    constexpr int MF = BM / 32;
    constexpr int NF = BN / 32;
    __shared__ __align__(16) unsigned short As[2][BM * BK];
    __shared__ __align__(16) unsigned short Bs[2][BN * BK];

    const int t = threadIdx.x;
    const int wid = t >> 6, lane = t & 63;
    const int m0 = blockIdx.x * BM, n0 = blockIdx.y * BN;
    const int wrow = (wid >> 1) * (BM / 2);
    const int wcol = (wid & 1) * (BN / 2);
    const int lr = lane & 15, lk = (lane >> 4) * 8;
    const int rx = (lr & 7) << 3;                       // read-side XOR

    // stage-side inverse permutation
    const int b0 = lane & 1, b1 = (lane >> 1) & 1, b2 = (lane >> 2) & 1;
    const int b3 = (lane >> 3) & 1, b4 = (lane >> 4) & 1, b5 = (lane >> 5) & 1;
    const int r0 = b2 ^ b4;
    const int swrow = r0 | (b3 << 1) | (b4 << 2) | (b5 << 3);      // 0..15
    const int swcol = ((b0 ^ r0) << 3) | ((b1 ^ b3) << 4);         // 0,8,16,24

    f32x4 acc[MF][NF];
#pragma unroll
    for (int m = 0; m < MF; ++m)
#pragma unroll
        for (int n = 0; n < NF; ++n) acc[m][n] = (f32x4){0.f, 0.f, 0.f, 0.f};

    const unsigned short* Ag = A + (size_t)m0 * K;
    const unsigned short* Wg = W + (size_t)n0 * K;

#define G_STAGE(k0_, buf_)                                                        \
    do {                                                                          \
        _Pragma("unroll")                                                         \
        for (int i = 0; i < BM / 64; ++i) {                                       \
            const int rb = i * 4 + wid;                                           \
            gload_lds16(Ag + (size_t)(rb * 16 + swrow) * K + (k0_) + swcol,       \
                        &As[buf_][(size_t)rb * 512]);                             \
        }                                                                         \
        _Pragma("unroll")                                                         \
        for (int i = 0; i < BN / 64; ++i) {                                       \
            const int rb = i * 4 + wid;                                           \
            gload_lds16(Wg + (size_t)(rb * 16 + swrow) * K + (k0_) + swcol,       \
                        &Bs[buf_][(size_t)rb * 512]);                             \
        }                                                                         \
    } while (0)

    const int nk = K / BK;
    G_STAGE(0, 0);
    __syncthreads();

    for (int ki = 0; ki < nk; ++ki) {
        const int cur = ki & 1;
        if (ki + 1 < nk) G_STAGE((ki + 1) * BK, cur ^ 1);   // overlaps compute

        bf16x8 af[MF], bf[NF];
#pragma unroll
        for (int m = 0; m < MF; ++m)
            af[m] = *(const bf16x8*)&As[cur][(((wrow + m * 16 + lr) * BK + lk) ^ rx)];
#pragma unroll
        for (int n = 0; n < NF; ++n)
            bf[n] = *(const bf16x8*)&Bs[cur][(((wcol + n * 16 + lr) * BK + lk) ^ rx)];
#pragma unroll
        for (int m = 0; m < MF; ++m)
#pragma unroll
            for (int n = 0; n < NF; ++n)
                acc[m][n] = __builtin_amdgcn_mfma_f32_16x16x32_bf16(af[m], bf[n], acc[m][n], 0, 0, 0);
        __syncthreads();
    }
#undef G_STAGE

    const int orow0 = m0 + wrow + (lane >> 4) * 4;
    const int ocol0 = n0 + wcol + lr;
#pragma unroll
    for (int m = 0; m < MF; ++m)
#pragma unroll
        for (int n = 0; n < NF; ++n)
#pragma unroll
            for (int i = 0; i < 4; ++i) {
                const size_t idx = (size_t)(orow0 + m * 16 + i) * N + ocol0 + n * 16;
                if (OUTMODE == 1) ((unsigned short*)Cout)[idx] = f2b(acc[m][n][i]);
                else              ((float*)Cout)[idx] = acc[m][n][i];
            }
}

// ------- FUSED projections, BK=32, swizzled: qk(+LN) [0,512) | v [512,1024) -------
__global__ __launch_bounds__(256) void proj_fused(const unsigned short* __restrict__ xh,
                                                  const unsigned short* __restrict__ xl,
                                                  const unsigned short* __restrict__ Wh,
                                                  const unsigned short* __restrict__ Wl,
                                                  const unsigned short* __restrict__ Wvb,
                                                  const float* __restrict__ gamma,
                                                  const float* __restrict__ beta,
                                                  unsigned short* __restrict__ qhl,
                                                  unsigned short* __restrict__ khl,
                                                  unsigned short* __restrict__ vT) {
    __shared__ __align__(16) unsigned short smem[16384];   // 32 KB arena
    const int t = threadIdx.x;
    const int wid = t >> 6, lane = t & 63;
    const int lr = lane & 15, lk = (lane >> 4) * 8;
    const int rx = (lr & 7) << 3;
    constexpr int K = 1024, BK = 32;
    const int nk = K / BK;   // 32

    const int b0 = lane & 1, b1 = (lane >> 1) & 1, b2 = (lane >> 2) & 1;
    const int b3 = (lane >> 3) & 1, b4 = (lane >> 4) & 1, b5 = (lane >> 5) & 1;
    const int r0 = b2 ^ b4;
    const int swrow = r0 | (b3 << 1) | (b4 << 2) | (b5 << 3);
    const int swcol = ((b0 ^ r0) << 3) | ((b1 ^ b3) << 4);

    if (blockIdx.x < 512) {
        // ================= qk + LN (BM=BN=64, split hi/lo) =================
        const int bx = blockIdx.x & 63, by = blockIdx.x >> 6;
        const int m0 = bx * 64, n0 = by * 64;
        unsigned short* Ahs = smem;             // [2][2048]
        unsigned short* Als = smem + 4096;
        unsigned short* Bhs = smem + 8192;
        unsigned short* Bls = smem + 12288;
        const int wrow = (wid >> 1) * 32;
        const int wcol = (wid & 1) * 32;

        f32x4 acc[2][2];
#pragma unroll
        for (int m = 0; m < 2; ++m)
#pragma unroll
            for (int n = 0; n < 2; ++n) acc[m][n] = (f32x4){0.f, 0.f, 0.f, 0.f};

        const unsigned short* Ahg = xh + (size_t)m0 * K;
        const unsigned short* Alg = xl + (size_t)m0 * K;
        const unsigned short* Whg = Wh + (size_t)n0 * K;
        const unsigned short* Wlg = Wl + (size_t)n0 * K;

#define S_STAGE(k0_, buf_)                                                        \
    do {                                                                          \
        const size_t go = (size_t)(wid * 16 + swrow) * K + (k0_) + swcol;         \
        const size_t lo = (size_t)((buf_) * 2048 + wid * 512);                    \
        gload_lds16(Ahg + go, Ahs + lo);                                          \
        gload_lds16(Alg + go, Als + lo);                                          \
        gload_lds16(Whg + go, Bhs + lo);                                          \
        gload_lds16(Wlg + go, Bls + lo);                                          \
    } while (0)

        S_STAGE(0, 0);
        __syncthreads();

        for (int ki = 0; ki < nk; ++ki) {
            const int cur = ki & 1;
            if (ki + 1 < nk) S_STAGE((ki + 1) * BK, cur ^ 1);

            bf16x8 afh[2], afl[2], bfh[2], bfl[2];
#pragma unroll
            for (int m = 0; m < 2; ++m) {
                const int ia = ((wrow + m * 16 + lr) * BK + lk) ^ rx;
                afh[m] = *(const bf16x8*)&Ahs[cur * 2048 + ia];
                afl[m] = *(const bf16x8*)&Als[cur * 2048 + ia];
            }
#pragma unroll
            for (int n = 0; n < 2; ++n) {
                const int ib = ((wcol + n * 16 + lr) * BK + lk) ^ rx;
                bfh[n] = *(const bf16x8*)&Bhs[cur * 2048 + ib];
                bfl[n] = *(const bf16x8*)&Bls[cur * 2048 + ib];
            }
#pragma unroll
            for (int m = 0; m < 2; ++m)
#pragma unroll
                for (int n = 0; n < 2; ++n) {
                    acc[m][n] = __builtin_amdgcn_mfma_f32_16x16x32_bf16(afh[m], bfh[n], acc[m][n], 0, 0, 0);
                    acc[m][n] = __builtin_amdgcn_mfma_f32_16x16x32_bf16(afh[m], bfl[n], acc[m][n], 0, 0, 0);
                    acc[m][n] = __builtin_amdgcn_mfma_f32_16x16x32_bf16(afl[m], bfh[n], acc[m][n], 0, 0, 0);
                }
            __syncthreads();
        }
#undef S_STAGE

        // fused LN + hi/lo split epilogue (lanes lr=0..15 hold one head's 16 cols)
        const int orow0 = m0 + wrow + (lane >> 4) * 4;
        const float gl = gamma[lr];
        const float bl = beta[lr];
#pragma unroll
        for (int n = 0; n < 2; ++n) {
            const int head_all = (n0 + wcol + n * 16) >> 4;
            const float scale = (head_all < 16) ? 0.25f : 1.0f;
            unsigned short* base = (head_all < 16) ? qhl : khl;
            const size_t hoff = (size_t)(head_all & 15) * (2048 * 32);
#pragma unroll
            for (int m = 0; m < 2; ++m)
#pragma unroll
                for (int i = 0; i < 4; ++i) {
                    const float v = acc[m][n][i];
                    float s = v, sq = v * v;
#pragma unroll
                    for (int msk = 1; msk < 16; msk <<= 1) {
                        s  += __shfl_xor(s,  msk);
                        sq += __shfl_xor(sq, msk);
                    }
                    const float mu  = s * 0.0625f;
                    const float var = sq * 0.0625f - mu * mu;
                    const float rs  = rsqrtf(var + 1e-5f);
                    const float val = ((v - mu) * rs * gl + bl) * scale;
                    const unsigned short hb = f2b(val);
                    const unsigned short lb = f2b(val - b2f(hb));
                    const int mrow = orow0 + m * 16 + i;
                    const int bb = mrow >> 11, l = mrow & 2047;
                    unsigned short* dst = base + (size_t)bb * (16 * 2048 * 32) + hoff + (size_t)l * 32;
                    dst[lr]      = hb;
                    dst[16 + lr] = lb;
                }
        }
    } else {
        // ================= v projection (BM=128, BN=64) -> vT =================
        const int idx = blockIdx.x - 512;
        const int bx = idx & 31, by = idx >> 5;
        const int m0 = bx * 128, n0 = by * 64;
        unsigned short* As = smem;              // [2][4096]
        unsigned short* Bs = smem + 8192;       // [2][2048]
        const int wrow = (wid >> 1) * 64;
        const int wcol = (wid & 1) * 32;

        f32x4 acc[4][2];
#pragma unroll
        for (int m = 0; m < 4; ++m)
#pragma unroll
            for (int n = 0; n < 2; ++n) acc[m][n] = (f32x4){0.f, 0.f, 0.f, 0.f};

        const unsigned short* Ag = xh + (size_t)m0 * K;
        const unsigned short* Wg = Wvb + (size_t)n0 * K;

#define V_STAGE(k0_, buf_)                                                        \
    do {                                                                          \
        _Pragma("unroll")                                                         \
        for (int i = 0; i < 2; ++i) {                                             \
            const int rb = i * 4 + wid;                                           \
            gload_lds16(Ag + (size_t)(rb * 16 + swrow) * K + (k0_) + swcol,       \
                        As + (size_t)((buf_) * 4096 + rb * 512));                 \
        }                                                                         \
        gload_lds16(Wg + (size_t)(wid * 16 + swrow) * K + (k0_) + swcol,          \
                    Bs + (size_t)((buf_) * 2048 + wid * 512));                    \
    } while (0)

        V_STAGE(0, 0);
        __syncthreads();

        for (int ki = 0; ki < nk; ++ki) {
            const int cur = ki & 1;
            if (ki + 1 < nk) V_STAGE((ki + 1) * BK, cur ^ 1);

            bf16x8 af[4], bf[2];
#pragma unroll
            for (int m = 0; m < 4; ++m)
                af[m] = *(const bf16x8*)&As[cur * 4096 + (((wrow + m * 16 + lr) * BK + lk) ^ rx)];
#pragma unroll
            for (int n = 0; n < 2; ++n)
                bf[n] = *(const bf16x8*)&Bs[cur * 2048 + (((wcol + n * 16 + lr) * BK + lk) ^ rx)];
#pragma unroll
            for (int m = 0; m < 4; ++m)
#pragma unroll
                for (int n = 0; n < 2; ++n)
                    acc[m][n] = __builtin_amdgcn_mfma_f32_16x16x32_bf16(af[m], bf[n], acc[m][n], 0, 0, 0);
            __syncthreads();
        }
#undef V_STAGE

        const int orow0 = m0 + wrow + (lane >> 4) * 4;
        const int ocol0 = n0 + wcol + lr;
#pragma unroll
        for (int m = 0; m < 4; ++m)
#pragma unroll
            for (int n = 0; n < 2; ++n) {
                const int nc = ocol0 + n * 16;
                const int mrow = orow0 + m * 16;
                unsigned short* dst = vT
                    + (size_t)((mrow >> 11) * 16 + (nc >> 6)) * (64 * 2048)
                    + (size_t)(nc & 63) * 2048 + (mrow & 2047);
                ushort4v pv;
#pragma unroll
                for (int i = 0; i < 4; ++i) pv[i] = f2b(acc[m][n][i]);
                *(ushort4v*)dst = pv;
            }
    }
}

// ---------------- fused casts: one launch ----------------
__global__ __launch_bounds__(256) void mega_cast(const float* __restrict__ x,
                                                 const float* __restrict__ Wq,
                                                 const float* __restrict__ Wk,
                                                 const float* __restrict__ Wv,
                                                 const float* __restrict__ Wo,
                                                 unsigned short* __restrict__ xh,
                                                 unsigned short* __restrict__ xl,
                                                 unsigned short* __restrict__ wqkh,
                                                 unsigned short* __restrict__ wqkl,
                                                 unsigned short* __restrict__ wvb,
                                                 unsigned short* __restrict__ wob) {
    const int blk = blockIdx.x;
    if (blk < 2048) {
        const int i = (blk * 256 + threadIdx.x) * 8;
        float4 a = *(const float4*)(x + i);
        float4 b = *(const float4*)(x + i + 4);
        float xv[8] = {a.x, a.y, a.z, a.w, b.x, b.y, b.z, b.w};
        ushort8 oh, ol;
#pragma unroll
        for (int e = 0; e < 8; ++e) {
            const unsigned short h = f2b(xv[e]);
            oh[e] = h;
            ol[e] = f2b(xv[e] - b2f(h));
        }
        *(ushort8*)(xh + i) = oh;
        *(ushort8*)(xl + i) = ol;
    } else if (blk < 2304) {
        const int i = ((blk - 2048) * 256 + threadIdx.x) * 8;
        const float* in = (i < 256 * 1024) ? Wq : Wk;
        const int j = (i < 256 * 1024) ? i : (i - 256 * 1024);
        float4 p = *(const float4*)(in + j);
        float4 q = *(const float4*)(in + j + 4);
        float xv[8] = {p.x, p.y, p.z, p.w, q.x, q.y, q.z, q.w};
        ushort8 oh, ol;
#pragma unroll
        for (int e = 0; e < 8; ++e) {
            const unsigned short h = f2b(xv[e]);
            oh[e] = h;
            ol[e] = f2b(xv[e] - b2f(h));
        }
        *(ushort8*)(wqkh + i) = oh;
        *(ushort8*)(wqkl + i) = ol;
    } else {
        const int i = ((blk - 2304) * 256 + threadIdx.x) * 8;
        const float* in = (i < 1024 * 1024) ? Wv : Wo;
        unsigned short* out = (i < 1024 * 1024) ? wvb : wob;
        const int j = (i < 1024 * 1024) ? i : (i - 1024 * 1024);
        float4 p = *(const float4*)(in + j);
        float4 q = *(const float4*)(in + j + 4);
        ushort8 o;
        o[0] = f2b(p.x); o[1] = f2b(p.y); o[2] = f2b(p.z); o[3] = f2b(p.w);
        o[4] = f2b(q.x); o[5] = f2b(q.y); o[6] = f2b(q.z); o[7] = f2b(q.w);
        *(ushort8*)(out + j) = o;
    }
}

// ------- causal (q.k)^2 attention: 32x32 MFMA, P-in-register, 8-wave blocks -------
// (r15/r17 verified, ~34us)
__global__ __launch_bounds__(512) void rebased_attn(const unsigned short* __restrict__ qhl_g,
                                                    const unsigned short* __restrict__ khl_g,
                                                    const unsigned short* __restrict__ vT,
                                                    unsigned short* __restrict__ o) {
    const int bh = blockIdx.x;
    const int x  = blockIdx.y;
    const int bb = bh >> 4;
    const int t = threadIdx.x;
    const int wid = t >> 6, lane = t & 63;
    const int lq = lane & 31, lh = lane >> 5;
    const int tq = wid >> 1, qs = wid & 1;
    const int qt = (tq == 0) ? x : (tq == 1) ? (15 - x) : (tq == 2) ? (16 + x) : (31 - x);
    const int qtmax = 31 - x;

    __shared__ __align__(16) unsigned short khl[3][4 * 64 * 8];
    __shared__ __align__(16) unsigned short vsl[3][8 * 64 * 8];
    __shared__ float zbuf[8][32];

    const unsigned short* qg  = qhl_g + (size_t)bh * 2048 * 32;
    const unsigned short* kg  = khl_g + (size_t)bh * 2048 * 32;
    const unsigned short* vbh = vT + (size_t)bh * 64 * 2048;
    unsigned short*       obh = o  + (size_t)bb * 2048 * 1024 + (bh & 15) * 64;

    const f32x16 zc16 = (f32x16)(0.f);

    const unsigned short* qr_ = qg + (size_t)(qt * 64 + qs * 32 + lq) * 32;
    const bf16x8 bqh = *(const bf16x8*)&qr_[lh * 8];
    const bf16x8 bql = *(const bf16x8*)&qr_[16 + lh * 8];

#define STAGE_KV(kt_, buf_)                                                            \
    do {                                                                               \
        if (wid < 4)                                                                   \
            gload_lds16(kg + ((size_t)((kt_) << 6) + lane) * 32 + wid * 8,             \
                        &khl[buf_][wid * 512]);                                        \
        gload_lds16(vbh + (size_t)lane * 2048 + ((kt_) << 6) + wid * 8,                \
                    &vsl[buf_][wid * 512]);                                            \
    } while (0)

    STAGE_KV(0, 0);
    STAGE_KV(1, 1);
    if (wid < 4) asm volatile("s_waitcnt vmcnt(2)" ::: "memory");
    else         asm volatile("s_waitcnt vmcnt(1)" ::: "memory");
    __builtin_amdgcn_s_barrier();

    f32x16 oacc[2];
    oacc[0] = zc16; oacc[1] = zc16;
    float zl = 0.f;

    for (int kt = 0; kt <= qtmax; ++kt) {
        const int cur = kt % 3;
        const bool pf = (kt + 2 <= qtmax);
        if (pf) STAGE_KV(kt + 2, (kt + 2) % 3);

        if (kt <= qt) {
            __builtin_amdgcn_s_setprio(1);
            f32x16 D[2];
#pragma unroll
            for (int st = 0; st < 2; ++st) {
                const bf16x8 kh = *(const bf16x8*)&khl[cur][((lh    ) * 64 + st * 32 + lq) * 8];
                const bf16x8 kl = *(const bf16x8*)&khl[cur][((2 + lh) * 64 + st * 32 + lq) * 8];
                f32x16 a = __builtin_amdgcn_mfma_f32_32x32x16_bf16(kh, bql, zc16, 0, 0, 0);
                a = __builtin_amdgcn_mfma_f32_32x32x16_bf16(kl, bqh, a, 0, 0, 0);
                a = __builtin_amdgcn_mfma_f32_32x32x16_bf16(kh, bqh, a, 0, 0, 0);
                D[st] = a;
            }
            const bool diag = (kt == qt);
#pragma unroll
            for (int st = 0; st < 2; ++st)
#pragma unroll
                for (int r = 0; r < 16; ++r) {
                    const float v = D[st][r];
                    float s2 = v * v;
                    if (diag) {
                        const int kr = st * 32 + (r & 3) + 8 * (r >> 2) + 4 * lh;
                        s2 = (kr <= qs * 32 + lq) ? s2 : 0.f;
                    }
                    zl += s2;
                    D[st][r] = s2;
                }
#pragma unroll
            for (int ks = 0; ks < 4; ++ks) {
                const int st = ks >> 1, b = 8 * (ks & 1);
                const bf16x8 vb0 = *(const bf16x8*)&vsl[cur][((2 * ks + lh) * 64 + 0 * 32 + lq) * 8];
                const bf16x8 vb1 = *(const bf16x8*)&vsl[cur][((2 * ks + lh) * 64 + 1 * 32 + lq) * 8];
                unsigned u0 = pk2(D[st][b + 0], D[st][b + 1]);
                unsigned u1 = pk2(D[st][b + 2], D[st][b + 3]);
                unsigned v0 = pk2(D[st][b + 4], D[st][b + 5]);
                unsigned v1 = pk2(D[st][b + 6], D[st][b + 7]);
                asm("v_permlane32_swap_b32 %0, %1" : "+v"(u0), "+v"(v0));
                asm("v_permlane32_swap_b32 %0, %1" : "+v"(u1), "+v"(v1));
                uint4v pw; pw[0] = u0; pw[1] = u1; pw[2] = v0; pw[3] = v1;
                const bf16x8 pa = __builtin_bit_cast(bf16x8, pw);
                oacc[0] = __builtin_amdgcn_mfma_f32_32x32x16_bf16(pa, vb0, oacc[0], 0, 0, 0);
                oacc[1] = __builtin_amdgcn_mfma_f32_32x32x16_bf16(pa, vb1, oacc[1], 0, 0, 0);
            }
            __builtin_amdgcn_s_setprio(0);
        }

        if (pf) {
            if (wid < 4) asm volatile("s_waitcnt vmcnt(2)" ::: "memory");
            else         asm volatile("s_waitcnt vmcnt(1)" ::: "memory");
        } else {
            asm volatile("s_waitcnt vmcnt(0)" ::: "memory");
        }
        __builtin_amdgcn_s_barrier();
    }
#undef STAGE_KV

    {
        const float z = zl + __shfl_xor(zl, 32);
        if (lh == 0) zbuf[wid][lq] = 1.f / (z + 1e-5f);
    }
#pragma unroll
    for (int dt = 0; dt < 2; ++dt)
#pragma unroll
        for (int r = 0; r < 16; ++r) {
            const int qr = (r & 3) + 8 * (r >> 2) + 4 * lh;
            const float zi = zbuf[wid][qr];
            obh[(size_t)(qt * 64 + qs * 32 + qr) * 1024 + dt * 32 + lq] =
                f2b(oacc[dt][r] * zi);
        }
}

extern "C" void kernel_launch(void* const* d_in, const int* in_sizes, int n_in,
                              void* d_out, int out_size, void* d_ws, size_t ws_size,
                              hipStream_t stream) {
    const float* x     = (const float*)d_in[0];
    const float* Wq    = (const float*)d_in[1];
    const float* Wk    = (const float*)d_in[2];
    const float* Wv    = (const float*)d_in[3];
    const float* Wo    = (const float*)d_in[4];
    const float* gamma = (const float*)d_in[5];
    const float* beta  = (const float*)d_in[6];
    float* out = (float*)d_out;
    (void)in_sizes; (void)n_in; (void)out_size; (void)ws_size;

    char* w = (char*)d_ws;
    unsigned short* vTb    = (unsigned short*)(w + (8u  << 20));          // 8 MB
    unsigned short* ob     = (unsigned short*)(w + (16u << 20));          // 8 MB
    unsigned short* xh     = (unsigned short*)(w + (24u << 20));          // 8 MB
    unsigned short* xl     = (unsigned short*)(w + (32u << 20));          // 8 MB
    unsigned short* qhl_g  = (unsigned short*)(w + (0u  << 20));          // 4 MB
    unsigned short* khl_g  = (unsigned short*)(w + (4u  << 20));          // 4 MB
    unsigned short* wqkh   = (unsigned short*)(w + (40u << 20));          // 1 MB
    unsigned short* wqkl   = (unsigned short*)(w + (41u << 20));          // 1 MB
    unsigned short* wvb    = (unsigned short*)(w + (42u << 20));          // 2 MB
    unsigned short* wob    = (unsigned short*)(w + (44u << 20));          // 2 MB

    // all casts in one launch
    mega_cast<<<3328, 256, 0, stream>>>(x, Wq, Wk, Wv, Wo,
                                        xh, xl, wqkh, wqkl, wvb, wob);

    // qk(+LN) and v projections fused into ONE dispatch (BK=32, swizzled LDS)
    proj_fused<<<1024, 256, 0, stream>>>(xh, xl, wqkh, wqkl, wvb,
                                         gamma, beta, qhl_g, khl_g, vTb);

    // attention -> bf16 ob; 8-wave quad blocks (r15 verified)
    rebased_attn<<<dim3(32, 8), 512, 0, stream>>>(qhl_g, khl_g, vTb, ob);

    // output projection -> f32 out; 128x64 tiles, BK=32, swizzled LDS
    gemm_mfma<128, 64, 0><<<dim3(32, 16), 256, 0, stream>>>(ob, wob, out, 4096, 1024, 1024);
}

// Round 21
// 100.471 us; speedup vs baseline: 1.0077x; 1.0077x over previous
//
#include <hip/hip_runtime.h>
#include <cstddef>
#include <cstdint>

// ReBased linear attention, round 21.
// r20 post-mortem: conflicts identical pre/post swizzle -> proj_fused is
// LDS-VOLUME-bound, not conflict-bound (~917k ds_read_b128 total). Fix:
// raise fragment-read density via bigger tiles:
//   qk branch: BM=128,BN=64  -> 12 reads / 24 MFMA (was 8/12), 256 blocks
//   v  branch: BM=128,BN=128 -> 8 reads / 16 MFMA (was 6/8),  256 blocks
// Arena 48KB, grid 512 = 2 blocks/CU (r18/r19: 2-vs-5 blocks/CU ~flat).
// Total b128 reads -29%, staging loads -25%. attn / o-GEMM / mega_cast frozen.

typedef __attribute__((ext_vector_type(8)))  __bf16 bf16x8;
typedef __attribute__((ext_vector_type(2)))  __bf16 bf16x2;
typedef __attribute__((ext_vector_type(4)))  float  f32x4;
typedef __attribute__((ext_vector_type(16))) float  f32x16;
typedef __attribute__((ext_vector_type(8)))  unsigned short ushort8;
typedef __attribute__((ext_vector_type(4)))  unsigned short ushort4v;
typedef __attribute__((ext_vector_type(4)))  unsigned int   uint4v;

__device__ __forceinline__ unsigned short f2b(float f) {
    union { float f; unsigned u; } v; v.f = f;
    unsigned r = v.u + 0x7FFFu + ((v.u >> 16) & 1u);   // RNE
    return (unsigned short)(r >> 16);
}
__device__ __forceinline__ float b2f(unsigned short b) {
    union { unsigned u; float f; } v; v.u = ((unsigned)b) << 16;
    return v.f;
}
__device__ __forceinline__ unsigned pk2(float a, float b) {
    bf16x2 p; p[0] = (__bf16)a; p[1] = (__bf16)b;
    return __builtin_bit_cast(unsigned, p);
}

typedef const __attribute__((address_space(1))) void* gas_ptr;
typedef __attribute__((address_space(3))) void* las_ptr;

__device__ __forceinline__ void gload_lds16(const unsigned short* g, unsigned short* l) {
    // 16B/lane; LDS dest = wave-uniform base + lane*16
    __builtin_amdgcn_global_load_lds((gas_ptr)g, (las_ptr)l, 16, 0, 0);
}

// Swizzle (ushort-index domain, BK=32 tiles, 64B rows) -- verified r20:
//   read:  idx = (row*32 + col) ^ ((row&7)<<3)
//   stage: lane l in a 16-row block rb: logical row = rb*16 + ((l2^l4)|(l3<<1)|(l4<<2)|(l5<<3)),
//          col = ((l0^l2^l4)<<3)|((l1^l3)<<4)

// ---------------- bf16 MFMA GEMM, BK=32, swizzled (o-projection, frozen) ----------------
template <int BM, int BN, int OUTMODE>
__global__ __launch_bounds__(256) void gemm_mfma(const unsigned short* __restrict__ A,
                                                 const unsigned short* __restrict__ W,
                                                 void* __restrict__ Cout,
                                                 int M, int N, int K) {
    constexpr int BK = 32;
    constexpr int MF = BM / 32;
    constexpr int NF = BN / 32;
    __shared__ __align__(16) unsigned short As[2][BM * BK];
    __shared__ __align__(16) unsigned short Bs[2][BN * BK];

    const int t = threadIdx.x;
    const int wid = t >> 6, lane = t & 63;
    const int m0 = blockIdx.x * BM, n0 = blockIdx.y * BN;
    const int wrow = (wid >> 1) * (BM / 2);
    const int wcol = (wid & 1) * (BN / 2);
    const int lr = lane & 15, lk = (lane >> 4) * 8;
    const int rx = (lr & 7) << 3;

    const int b0 = lane & 1, b1 = (lane >> 1) & 1, b2 = (lane >> 2) & 1;
    const int b3 = (lane >> 3) & 1, b4 = (lane >> 4) & 1, b5 = (lane >> 5) & 1;
    const int r0 = b2 ^ b4;
    const int swrow = r0 | (b3 << 1) | (b4 << 2) | (b5 << 3);
    const int swcol = ((b0 ^ r0) << 3) | ((b1 ^ b3) << 4);

    f32x4 acc[MF][NF];
#pragma unroll
    for (int m = 0; m < MF; ++m)
#pragma unroll
        for (int n = 0; n < NF; ++n) acc[m][n] = (f32x4){0.f, 0.f, 0.f, 0.f};

    const unsigned short* Ag = A + (size_t)m0 * K;
    const unsigned short* Wg = W + (size_t)n0 * K;

#define G_STAGE(k0_, buf_)                                                        \
    do {                                                                          \
        _Pragma("unroll")                                                         \
        for (int i = 0; i < BM / 64; ++i) {                                       \
            const int rb = i * 4 + wid;                                           \
            gload_lds16(Ag + (size_t)(rb * 16 + swrow) * K + (k0_) + swcol,       \
                        &As[buf_][(size_t)rb * 512]);                             \
        }                                                                         \
        _Pragma("unroll")                                                         \
        for (int i = 0; i < BN / 64; ++i) {                                       \
            const int rb = i * 4 + wid;                                           \
            gload_lds16(Wg + (size_t)(rb * 16 + swrow) * K + (k0_) + swcol,       \
                        &Bs[buf_][(size_t)rb * 512]);                             \
        }                                                                         \
    } while (0)

    const int nk = K / BK;
    G_STAGE(0, 0);
    __syncthreads();

    for (int ki = 0; ki < nk; ++ki) {
        const int cur = ki & 1;
        if (ki + 1 < nk) G_STAGE((ki + 1) * BK, cur ^ 1);

        bf16x8 af[MF], bf[NF];
#pragma unroll
        for (int m = 0; m < MF; ++m)
            af[m] = *(const bf16x8*)&As[cur][(((wrow + m * 16 + lr) * BK + lk) ^ rx)];
#pragma unroll
        for (int n = 0; n < NF; ++n)
            bf[n] = *(const bf16x8*)&Bs[cur][(((wcol + n * 16 + lr) * BK + lk) ^ rx)];
#pragma unroll
        for (int m = 0; m < MF; ++m)
#pragma unroll
            for (int n = 0; n < NF; ++n)
                acc[m][n] = __builtin_amdgcn_mfma_f32_16x16x32_bf16(af[m], bf[n], acc[m][n], 0, 0, 0);
        __syncthreads();
    }
#undef G_STAGE

    const int orow0 = m0 + wrow + (lane >> 4) * 4;
    const int ocol0 = n0 + wcol + lr;
#pragma unroll
    for (int m = 0; m < MF; ++m)
#pragma unroll
        for (int n = 0; n < NF; ++n)
#pragma unroll
            for (int i = 0; i < 4; ++i) {
                const size_t idx = (size_t)(orow0 + m * 16 + i) * N + ocol0 + n * 16;
                if (OUTMODE == 1) ((unsigned short*)Cout)[idx] = f2b(acc[m][n][i]);
                else              ((float*)Cout)[idx] = acc[m][n][i];
            }
}

// ------- FUSED projections, BK=32, swizzled, dense tiles -------
// qk(+LN) blocks [0,256): BM=128, BN=64.  v blocks [256,512): BM=128, BN=128.
__global__ __launch_bounds__(256) void proj_fused(const unsigned short* __restrict__ xh,
                                                  const unsigned short* __restrict__ xl,
                                                  const unsigned short* __restrict__ Wh,
                                                  const unsigned short* __restrict__ Wl,
                                                  const unsigned short* __restrict__ Wvb,
                                                  const float* __restrict__ gamma,
                                                  const float* __restrict__ beta,
                                                  unsigned short* __restrict__ qhl,
                                                  unsigned short* __restrict__ khl,
                                                  unsigned short* __restrict__ vT) {
    __shared__ __align__(16) unsigned short smem[24576];   // 48 KB arena
    const int t = threadIdx.x;
    const int wid = t >> 6, lane = t & 63;
    const int lr = lane & 15, lk = (lane >> 4) * 8;
    const int rx = (lr & 7) << 3;
    constexpr int K = 1024, BK = 32;
    const int nk = K / BK;   // 32

    const int b0 = lane & 1, b1 = (lane >> 1) & 1, b2 = (lane >> 2) & 1;
    const int b3 = (lane >> 3) & 1, b4 = (lane >> 4) & 1, b5 = (lane >> 5) & 1;
    const int r0 = b2 ^ b4;
    const int swrow = r0 | (b3 << 1) | (b4 << 2) | (b5 << 3);
    const int swcol = ((b0 ^ r0) << 3) | ((b1 ^ b3) << 4);

    if (blockIdx.x < 256) {
        // ============ qk + LN (BM=128, BN=64, split hi/lo) ============
        const int bx = blockIdx.x & 31, by = blockIdx.x >> 5;   // M/128=32, N/64=8
        const int m0 = bx * 128, n0 = by * 64;
        unsigned short* Ahs = smem;              // [2][4096] (128x32)
        unsigned short* Als = smem + 8192;       // [2][4096]
        unsigned short* Bhs = smem + 16384;      // [2][2048] (64x32)
        unsigned short* Bls = smem + 20480;      // [2][2048]
        const int wrow = (wid >> 1) * 64;
        const int wcol = (wid & 1) * 32;

        f32x4 acc[4][2];
#pragma unroll
        for (int m = 0; m < 4; ++m)
#pragma unroll
            for (int n = 0; n < 2; ++n) acc[m][n] = (f32x4){0.f, 0.f, 0.f, 0.f};

        const unsigned short* Ahg = xh + (size_t)m0 * K;
        const unsigned short* Alg = xl + (size_t)m0 * K;
        const unsigned short* Whg = Wh + (size_t)n0 * K;
        const unsigned short* Wlg = Wl + (size_t)n0 * K;

#define S_STAGE(k0_, buf_)                                                        \
    do {                                                                          \
        _Pragma("unroll")                                                         \
        for (int i = 0; i < 2; ++i) {                                             \
            const int rb = i * 4 + wid;                                           \
            const size_t go = (size_t)(rb * 16 + swrow) * K + (k0_) + swcol;      \
            gload_lds16(Ahg + go, Ahs + (size_t)((buf_) * 4096 + rb * 512));      \
            gload_lds16(Alg + go, Als + (size_t)((buf_) * 4096 + rb * 512));      \
        }                                                                         \
        {                                                                         \
            const size_t go = (size_t)(wid * 16 + swrow) * K + (k0_) + swcol;     \
            gload_lds16(Whg + go, Bhs + (size_t)((buf_) * 2048 + wid * 512));     \
            gload_lds16(Wlg + go, Bls + (size_t)((buf_) * 2048 + wid * 512));     \
        }                                                                         \
    } while (0)

        S_STAGE(0, 0);
        __syncthreads();

        for (int ki = 0; ki < nk; ++ki) {
            const int cur = ki & 1;
            if (ki + 1 < nk) S_STAGE((ki + 1) * BK, cur ^ 1);

            bf16x8 afh[4], afl[4], bfh[2], bfl[2];
#pragma unroll
            for (int m = 0; m < 4; ++m) {
                const int ia = ((wrow + m * 16 + lr) * BK + lk) ^ rx;
                afh[m] = *(const bf16x8*)&Ahs[cur * 4096 + ia];
                afl[m] = *(const bf16x8*)&Als[cur * 4096 + ia];
            }
#pragma unroll
            for (int n = 0; n < 2; ++n) {
                const int ib = ((wcol + n * 16 + lr) * BK + lk) ^ rx;
                bfh[n] = *(const bf16x8*)&Bhs[cur * 2048 + ib];
                bfl[n] = *(const bf16x8*)&Bls[cur * 2048 + ib];
            }
#pragma unroll
            for (int m = 0; m < 4; ++m)
#pragma unroll
                for (int n = 0; n < 2; ++n) {
                    acc[m][n] = __builtin_amdgcn_mfma_f32_16x16x32_bf16(afh[m], bfh[n], acc[m][n], 0, 0, 0);
                    acc[m][n] = __builtin_amdgcn_mfma_f32_16x16x32_bf16(afh[m], bfl[n], acc[m][n], 0, 0, 0);
                    acc[m][n] = __builtin_amdgcn_mfma_f32_16x16x32_bf16(afl[m], bfh[n], acc[m][n], 0, 0, 0);
                }
            __syncthreads();
        }
#undef S_STAGE

        // fused LN + hi/lo split epilogue (lanes lr=0..15 hold one head's 16 cols)
        const int orow0 = m0 + wrow + (lane >> 4) * 4;
        const float gl = gamma[lr];
        const float bl = beta[lr];
#pragma unroll
        for (int n = 0; n < 2; ++n) {
            const int head_all = (n0 + wcol + n * 16) >> 4;     // 0..31
            const float scale = (head_all < 16) ? 0.25f : 1.0f;
            unsigned short* base = (head_all < 16) ? qhl : khl;
            const size_t hoff = (size_t)(head_all & 15) * (2048 * 32);
#pragma unroll
            for (int m = 0; m < 4; ++m)
#pragma unroll
                for (int i = 0; i < 4; ++i) {
                    const float v = acc[m][n][i];
                    float s = v, sq = v * v;
#pragma unroll
                    for (int msk = 1; msk < 16; msk <<= 1) {
                        s  += __shfl_xor(s,  msk);
                        sq += __shfl_xor(sq, msk);
                    }
                    const float mu  = s * 0.0625f;
                    const float var = sq * 0.0625f - mu * mu;
                    const float rs  = rsqrtf(var + 1e-5f);
                    const float val = ((v - mu) * rs * gl + bl) * scale;
                    const unsigned short hb = f2b(val);
                    const unsigned short lb = f2b(val - b2f(hb));
                    const int mrow = orow0 + m * 16 + i;
                    const int bb = mrow >> 11, l = mrow & 2047;
                    unsigned short* dst = base + (size_t)bb * (16 * 2048 * 32) + hoff + (size_t)l * 32;
                    dst[lr]      = hb;
                    dst[16 + lr] = lb;
                }
        }
    } else {
        // ============ v projection (BM=128, BN=128) -> vT ============
        const int idx = blockIdx.x - 256;
        const int bx = idx & 31, by = idx >> 5;   // M/128=32, N/128=8
        const int m0 = bx * 128, n0 = by * 128;
        unsigned short* As = smem;               // [2][4096]
        unsigned short* Bs = smem + 8192;        // [2][4096]
        const int wrow = (wid >> 1) * 64;
        const int wcol = (wid & 1) * 64;

        f32x4 acc[4][4];
#pragma unroll
        for (int m = 0; m < 4; ++m)
#pragma unroll
            for (int n = 0; n < 4; ++n) acc[m][n] = (f32x4){0.f, 0.f, 0.f, 0.f};

        const unsigned short* Ag = xh + (size_t)m0 * K;
        const unsigned short* Wg = Wvb + (size_t)n0 * K;

#define V_STAGE(k0_, buf_)                                                        \
    do {                                                                          \
        _Pragma("unroll")                                                         \
        for (int i = 0; i < 2; ++i) {                                             \
            const int rb = i * 4 + wid;                                           \
            const size_t go = (size_t)(rb * 16 + swrow) * K + (k0_) + swcol;      \
            gload_lds16(Ag + go, As + (size_t)((buf_) * 4096 + rb * 512));        \
            gload_lds16(Wg + go, Bs + (size_t)((buf_) * 4096 + rb * 512));        \
        }                                                                         \
    } while (0)

        V_STAGE(0, 0);
        __syncthreads();

        for (int ki = 0; ki < nk; ++ki) {
            const int cur = ki & 1;
            if (ki + 1 < nk) V_STAGE((ki + 1) * BK, cur ^ 1);

            bf16x8 af[4], bf[4];
#pragma unroll
            for (int m = 0; m < 4; ++m)
                af[m] = *(const bf16x8*)&As[cur * 4096 + (((wrow + m * 16 + lr) * BK + lk) ^ rx)];
#pragma unroll
            for (int n = 0; n < 4; ++n)
                bf[n] = *(const bf16x8*)&Bs[cur * 4096 + (((wcol + n * 16 + lr) * BK + lk) ^ rx)];
#pragma unroll
            for (int m = 0; m < 4; ++m)
#pragma unroll
                for (int n = 0; n < 4; ++n)
                    acc[m][n] = __builtin_amdgcn_mfma_f32_16x16x32_bf16(af[m], bf[n], acc[m][n], 0, 0, 0);
            __syncthreads();
        }
#undef V_STAGE

        const int orow0 = m0 + wrow + (lane >> 4) * 4;
        const int ocol0 = n0 + wcol + lr;
#pragma unroll
        for (int m = 0; m < 4; ++m)
#pragma unroll
            for (int n = 0; n < 4; ++n) {
                const int nc = ocol0 + n * 16;
                const int mrow = orow0 + m * 16;
                unsigned short* dst = vT
                    + (size_t)((mrow >> 11) * 16 + (nc >> 6)) * (64 * 2048)
                    + (size_t)(nc & 63) * 2048 + (mrow & 2047);
                ushort4v pv;
#pragma unroll
                for (int i = 0; i < 4; ++i) pv[i] = f2b(acc[m][n][i]);
                *(ushort4v*)dst = pv;
            }
    }
}

// ---------------- fused casts: one launch (frozen) ----------------
__global__ __launch_bounds__(256) void mega_cast(const float* __restrict__ x,
                                                 const float* __restrict__ Wq,
                                                 const float* __restrict__ Wk,
                                                 const float* __restrict__ Wv,
                                                 const float* __restrict__ Wo,
                                                 unsigned short* __restrict__ xh,
                                                 unsigned short* __restrict__ xl,
                                                 unsigned short* __restrict__ wqkh,
                                                 unsigned short* __restrict__ wqkl,
                                                 unsigned short* __restrict__ wvb,
                                                 unsigned short* __restrict__ wob) {
    const int blk = blockIdx.x;
    if (blk < 2048) {
        const int i = (blk * 256 + threadIdx.x) * 8;
        float4 a = *(const float4*)(x + i);
        float4 b = *(const float4*)(x + i + 4);
        float xv[8] = {a.x, a.y, a.z, a.w, b.x, b.y, b.z, b.w};
        ushort8 oh, ol;
#pragma unroll
        for (int e = 0; e < 8; ++e) {
            const unsigned short h = f2b(xv[e]);
            oh[e] = h;
            ol[e] = f2b(xv[e] - b2f(h));
        }
        *(ushort8*)(xh + i) = oh;
        *(ushort8*)(xl + i) = ol;
    } else if (blk < 2304) {
        const int i = ((blk - 2048) * 256 + threadIdx.x) * 8;
        const float* in = (i < 256 * 1024) ? Wq : Wk;
        const int j = (i < 256 * 1024) ? i : (i - 256 * 1024);
        float4 p = *(const float4*)(in + j);
        float4 q = *(const float4*)(in + j + 4);
        float xv[8] = {p.x, p.y, p.z, p.w, q.x, q.y, q.z, q.w};
        ushort8 oh, ol;
#pragma unroll
        for (int e = 0; e < 8; ++e) {
            const unsigned short h = f2b(xv[e]);
            oh[e] = h;
            ol[e] = f2b(xv[e] - b2f(h));
        }
        *(ushort8*)(wqkh + i) = oh;
        *(ushort8*)(wqkl + i) = ol;
    } else {
        const int i = ((blk - 2304) * 256 + threadIdx.x) * 8;
        const float* in = (i < 1024 * 1024) ? Wv : Wo;
        unsigned short* out = (i < 1024 * 1024) ? wvb : wob;
        const int j = (i < 1024 * 1024) ? i : (i - 1024 * 1024);
        float4 p = *(const float4*)(in + j);
        float4 q = *(const float4*)(in + j + 4);
        ushort8 o;
        o[0] = f2b(p.x); o[1] = f2b(p.y); o[2] = f2b(p.z); o[3] = f2b(p.w);
        o[4] = f2b(q.x); o[5] = f2b(q.y); o[6] = f2b(q.z); o[7] = f2b(q.w);
        *(ushort8*)(out + j) = o;
    }
}

// ------- causal (q.k)^2 attention: 32x32 MFMA, P-in-register, 8-wave blocks -------
// (r15/r17 verified, ~34us; frozen)
__global__ __launch_bounds__(512) void rebased_attn(const unsigned short* __restrict__ qhl_g,
                                                    const unsigned short* __restrict__ khl_g,
                                                    const unsigned short* __restrict__ vT,
                                                    unsigned short* __restrict__ o) {
    const int bh = blockIdx.x;
    const int x  = blockIdx.y;
    const int bb = bh >> 4;
    const int t = threadIdx.x;
    const int wid = t >> 6, lane = t & 63;
    const int lq = lane & 31, lh = lane >> 5;
    const int tq = wid >> 1, qs = wid & 1;
    const int qt = (tq == 0) ? x : (tq == 1) ? (15 - x) : (tq == 2) ? (16 + x) : (31 - x);
    const int qtmax = 31 - x;

    __shared__ __align__(16) unsigned short khl[3][4 * 64 * 8];
    __shared__ __align__(16) unsigned short vsl[3][8 * 64 * 8];
    __shared__ float zbuf[8][32];

    const unsigned short* qg  = qhl_g + (size_t)bh * 2048 * 32;
    const unsigned short* kg  = khl_g + (size_t)bh * 2048 * 32;
    const unsigned short* vbh = vT + (size_t)bh * 64 * 2048;
    unsigned short*       obh = o  + (size_t)bb * 2048 * 1024 + (bh & 15) * 64;

    const f32x16 zc16 = (f32x16)(0.f);

    const unsigned short* qr_ = qg + (size_t)(qt * 64 + qs * 32 + lq) * 32;
    const bf16x8 bqh = *(const bf16x8*)&qr_[lh * 8];
    const bf16x8 bql = *(const bf16x8*)&qr_[16 + lh * 8];

#define STAGE_KV(kt_, buf_)                                                            \
    do {                                                                               \
        if (wid < 4)                                                                   \
            gload_lds16(kg + ((size_t)((kt_) << 6) + lane) * 32 + wid * 8,             \
                        &khl[buf_][wid * 512]);                                        \
        gload_lds16(vbh + (size_t)lane * 2048 + ((kt_) << 6) + wid * 8,                \
                    &vsl[buf_][wid * 512]);                                            \
    } while (0)

    STAGE_KV(0, 0);
    STAGE_KV(1, 1);
    if (wid < 4) asm volatile("s_waitcnt vmcnt(2)" ::: "memory");
    else         asm volatile("s_waitcnt vmcnt(1)" ::: "memory");
    __builtin_amdgcn_s_barrier();

    f32x16 oacc[2];
    oacc[0] = zc16; oacc[1] = zc16;
    float zl = 0.f;

    for (int kt = 0; kt <= qtmax; ++kt) {
        const int cur = kt % 3;
        const bool pf = (kt + 2 <= qtmax);
        if (pf) STAGE_KV(kt + 2, (kt + 2) % 3);

        if (kt <= qt) {
            __builtin_amdgcn_s_setprio(1);
            f32x16 D[2];
#pragma unroll
            for (int st = 0; st < 2; ++st) {
                const bf16x8 kh = *(const bf16x8*)&khl[cur][((lh    ) * 64 + st * 32 + lq) * 8];
                const bf16x8 kl = *(const bf16x8*)&khl[cur][((2 + lh) * 64 + st * 32 + lq) * 8];
                f32x16 a = __builtin_amdgcn_mfma_f32_32x32x16_bf16(kh, bql, zc16, 0, 0, 0);
                a = __builtin_amdgcn_mfma_f32_32x32x16_bf16(kl, bqh, a, 0, 0, 0);
                a = __builtin_amdgcn_mfma_f32_32x32x16_bf16(kh, bqh, a, 0, 0, 0);
                D[st] = a;
            }
            const bool diag = (kt == qt);
#pragma unroll
            for (int st = 0; st < 2; ++st)
#pragma unroll
                for (int r = 0; r < 16; ++r) {
                    const float v = D[st][r];
                    float s2 = v * v;
                    if (diag) {
                        const int kr = st * 32 + (r & 3) + 8 * (r >> 2) + 4 * lh;
                        s2 = (kr <= qs * 32 + lq) ? s2 : 0.f;
                    }
                    zl += s2;
                    D[st][r] = s2;
                }
#pragma unroll
            for (int ks = 0; ks < 4; ++ks) {
                const int st = ks >> 1, b = 8 * (ks & 1);
                const bf16x8 vb0 = *(const bf16x8*)&vsl[cur][((2 * ks + lh) * 64 + 0 * 32 + lq) * 8];
                const bf16x8 vb1 = *(const bf16x8*)&vsl[cur][((2 * ks + lh) * 64 + 1 * 32 + lq) * 8];
                unsigned u0 = pk2(D[st][b + 0], D[st][b + 1]);
                unsigned u1 = pk2(D[st][b + 2], D[st][b + 3]);
                unsigned v0 = pk2(D[st][b + 4], D[st][b + 5]);
                unsigned v1 = pk2(D[st][b + 6], D[st][b + 7]);
                asm("v_permlane32_swap_b32 %0, %1" : "+v"(u0), "+v"(v0));
                asm("v_permlane32_swap_b32 %0, %1" : "+v"(u1), "+v"(v1));
                uint4v pw; pw[0] = u0; pw[1] = u1; pw[2] = v0; pw[3] = v1;
                const bf16x8 pa = __builtin_bit_cast(bf16x8, pw);
                oacc[0] = __builtin_amdgcn_mfma_f32_32x32x16_bf16(pa, vb0, oacc[0], 0, 0, 0);
                oacc[1] = __builtin_amdgcn_mfma_f32_32x32x16_bf16(pa, vb1, oacc[1], 0, 0, 0);
            }
            __builtin_amdgcn_s_setprio(0);
        }

        if (pf) {
            if (wid < 4) asm volatile("s_waitcnt vmcnt(2)" ::: "memory");
            else         asm volatile("s_waitcnt vmcnt(1)" ::: "memory");
        } else {
            asm volatile("s_waitcnt vmcnt(0)" ::: "memory");
        }
        __builtin_amdgcn_s_barrier();
    }
#undef STAGE_KV

    {
        const float z = zl + __shfl_xor(zl, 32);
        if (lh == 0) zbuf[wid][lq] = 1.f / (z + 1e-5f);
    }
#pragma unroll
    for (int dt = 0; dt < 2; ++dt)
#pragma unroll
        for (int r = 0; r < 16; ++r) {
            const int qr = (r & 3) + 8 * (r >> 2) + 4 * lh;
            const float zi = zbuf[wid][qr];
            obh[(size_t)(qt * 64 + qs * 32 + qr) * 1024 + dt * 32 + lq] =
                f2b(oacc[dt][r] * zi);
        }
}

extern "C" void kernel_launch(void* const* d_in, const int* in_sizes, int n_in,
                              void* d_out, int out_size, void* d_ws, size_t ws_size,
                              hipStream_t stream) {
    const float* x     = (const float*)d_in[0];
    const float* Wq    = (const float*)d_in[1];
    const float* Wk    = (const float*)d_in[2];
    const float* Wv    = (const float*)d_in[3];
    const float* Wo    = (const float*)d_in[4];
    const float* gamma = (const float*)d_in[5];
    const float* beta  = (const float*)d_in[6];
    float* out = (float*)d_out;
    (void)in_sizes; (void)n_in; (void)out_size; (void)ws_size;

    char* w = (char*)d_ws;
    unsigned short* vTb    = (unsigned short*)(w + (8u  << 20));          // 8 MB
    unsigned short* ob     = (unsigned short*)(w + (16u << 20));          // 8 MB
    unsigned short* xh     = (unsigned short*)(w + (24u << 20));          // 8 MB
    unsigned short* xl     = (unsigned short*)(w + (32u << 20));          // 8 MB
    unsigned short* qhl_g  = (unsigned short*)(w + (0u  << 20));          // 4 MB
    unsigned short* khl_g  = (unsigned short*)(w + (4u  << 20));          // 4 MB
    unsigned short* wqkh   = (unsigned short*)(w + (40u << 20));          // 1 MB
    unsigned short* wqkl   = (unsigned short*)(w + (41u << 20));          // 1 MB
    unsigned short* wvb    = (unsigned short*)(w + (42u << 20));          // 2 MB
    unsigned short* wob    = (unsigned short*)(w + (44u << 20));          // 2 MB

    // all casts in one launch
    mega_cast<<<3328, 256, 0, stream>>>(x, Wq, Wk, Wv, Wo,
                                        xh, xl, wqkh, wqkl, wvb, wob);

    // qk(+LN) and v projections fused, dense tiles (512 blocks)
    proj_fused<<<512, 256, 0, stream>>>(xh, xl, wqkh, wqkl, wvb,
                                        gamma, beta, qhl_g, khl_g, vTb);

    // attention -> bf16 ob; 8-wave quad blocks (r15 verified)
    rebased_attn<<<dim3(32, 8), 512, 0, stream>>>(qhl_g, khl_g, vTb, ob);

    // output projection -> f32 out; 128x64 tiles, BK=32, swizzled LDS
    gemm_mfma<128, 64, 0><<<dim3(32, 16), 256, 0, stream>>>(ob, wob, out, 4096, 1024, 1024);
}